// Round 2
// baseline (393.055 us; speedup 1.0000x reference)
//
#include <hip/hip_runtime.h>

// LevelLayer: space_emb FFN -> kNN(k=15, per-event) -> 2x GIN(residual) -> out FFN
// N=8192 nodes, 32 events x 256, LAT=64, HID=128, FIN=4, FOUT=4, SPACE=3.
// Input float dtype is RUNTIME-DETECTED (bf16 vs fp32) from W_g1a bit patterns;
// all floating inputs are upcast to a canonical fp32 copy in d_ws, outputs are
// stored as bf16 or fp32 per the same flag.
// Outputs concatenated in d_out: h[8192*64] | x_emb[8192*4] | ei[2*122880].

#define N_NODES 8192
#define NPE     256
#define NEV     32
#define KNN     15
#define LAT     64
#define HID     128
#define NK      (N_NODES*KNN)

#define CVT_TOTAL 74820          // total floating input elements
// byte offsets in ws
#define OFF_FLAG 0
#define OFF_CVT  64
#define OFF_HA   400000          // %16 == 0
#define OFF_HB   (OFF_HA + 2097152)
#define OFF_POS  (OFF_HB + 2097152)
#define OFF_NBR  (OFF_POS + 98304)
// float-element offsets inside the cvt region
#define FO_X     0
#define FO_SE1   32768
#define FO_BSE1  33024
#define FO_SE2   33088
#define FO_BSE2  37184
#define FO_G1A   37248
#define FO_BG1A  45440
#define FO_G1B   45568
#define FO_BG1B  53760
#define FO_G2A   53824
#define FO_BG2A  62016
#define FO_G2B   62144
#define FO_BG2B  70336
#define FO_OE1   70400
#define FO_BOE1  74496
#define FO_OE2   74560
#define FO_BOE2  74816

typedef unsigned short bf16;
typedef unsigned int   u32;

__device__ __forceinline__ float bf2f(bf16 s) {
    union { u32 u; float f; } v; v.u = ((u32)s) << 16; return v.f;
}
__device__ __forceinline__ bf16 f2bf(float f) {
    union { float f; u32 u; } v; v.f = f;
    u32 u = v.u + 0x7fffu + ((v.u >> 16) & 1u);   // RNE
    return (bf16)(u >> 16);
}

// -------- dtype detect: inspect W_g1a's minimal footprint (16 KB) ------------
__global__ __launch_bounds__(256) void k_detect(const u32* __restrict__ w, int* __restrict__ flag)
{
    __shared__ int red[256];
    const int tid = threadIdx.x;
    int c = 0;
    for (int i = tid; i < 4096; i += 256) {
        const u32 x = w[i];
        c += ((x >> 7)  & 0xffu) >= 0xC8u;   // low half as bf16: |v| >= 2^73 -> insane
        c += ((x >> 23) & 0xffu) >= 0xC8u;   // high half
    }
    red[tid] = c;
    __syncthreads();
    for (int s = 128; s > 0; s >>= 1) {
        if (tid < s) red[tid] += red[tid + s];
        __syncthreads();
    }
    if (tid == 0) *flag = (red[0] > 64) ? 1 : 0;   // 1 = inputs are fp32
}

// -------- convert all floating inputs to fp32 in ws --------------------------
struct CvtArgs { const void* src[17]; int off[18]; };

__global__ __launch_bounds__(256) void k_convert(CvtArgs a, const int* __restrict__ flag,
                                                 float* __restrict__ dst)
{
    const int i = blockIdx.x * 256 + threadIdx.x;
    if (i >= CVT_TOTAL) return;
    int t = 0;
    while (i >= a.off[t + 1]) ++t;
    const int l = i - a.off[t];
    dst[i] = (*flag) ? ((const float*)a.src[t])[l]
                     : bf2f(((const bf16*)a.src[t])[l]);
}

// -------- space_emb: h = leaky(x@W1+b1)@W2+b2, 4 nodes/block ------------------
__global__ __launch_bounds__(256) void k_space(
    const float* __restrict__ x,
    const float* __restrict__ W1, const float* __restrict__ b1,
    const float* __restrict__ W2, const float* __restrict__ b2,
    float* __restrict__ h, float* __restrict__ pos)
{
    __shared__ float sW1[4 * LAT];
    __shared__ float sW2[LAT * LAT];
    __shared__ float sb1[LAT], sb2[LAT];
    __shared__ float shid[4][LAT];
    const int tid = threadIdx.x;
    for (int i = tid; i < 4 * LAT; i += 256)   sW1[i] = W1[i];
    for (int i = tid; i < LAT * LAT; i += 256) sW2[i] = W2[i];
    if (tid < LAT) { sb1[tid] = b1[tid]; sb2[tid] = b2[tid]; }
    __syncthreads();
    const int ln = tid >> 6, f = tid & 63;
    const int node = blockIdx.x * 4 + ln;
    float acc = sb1[f];
    #pragma unroll
    for (int i = 0; i < 4; i++) acc = fmaf(x[node * 4 + i], sW1[i * LAT + f], acc);
    acc = acc > 0.f ? acc : 0.01f * acc;          // leaky
    shid[ln][f] = acc;
    __syncthreads();
    float a2 = sb2[f];
    #pragma unroll
    for (int j = 0; j < LAT; j++) a2 = fmaf(shid[ln][j], sW2[j * LAT + f], a2);
    h[node * LAT + f] = a2;
    if (f < 3) pos[node * 3 + f] = a2;
}

// -------- kNN: one block per event ------------------------------------------
__global__ __launch_bounds__(256) void k_knn(
    const float* __restrict__ pos, const int* __restrict__ flag,
    int* __restrict__ nbr, void* __restrict__ d_out)
{
    __shared__ float sp[NPE * 3];
    const int tid = threadIdx.x;
    const int eb = blockIdx.x * NPE;
    for (int i = tid; i < NPE * 3; i += NPE) sp[i] = pos[(size_t)eb * 3 + i];
    __syncthreads();
    const float px = sp[tid * 3], py = sp[tid * 3 + 1], pz = sp[tid * 3 + 2];
    float bd[KNN]; int bi[KNN];
    #pragma unroll
    for (int k = 0; k < KNN; k++) { bd[k] = 1e30f; bi[k] = 0; }
    for (int j = 0; j < NPE; j++) {
        if (j == tid) continue;                          // no self-loop
        const float dx = px - sp[j * 3], dy = py - sp[j * 3 + 1], dz = pz - sp[j * 3 + 2];
        // match numpy's fp32 ((x^2 + y^2) + z^2), contraction suppressed
        float dd = __fmul_rn(dx, dx);
        dd = __fadd_rn(dd, __fmul_rn(dy, dy));
        dd = __fadd_rn(dd, __fmul_rn(dz, dz));
        if (dd < bd[KNN - 1]) {                          // strict <: stable ties
            int p = KNN - 1;
            while (p > 0 && bd[p - 1] > dd) { bd[p] = bd[p - 1]; bi[p] = bi[p - 1]; --p; }
            bd[p] = dd; bi[p] = eb + j;
        }
    }
    const int gi = eb + tid;
    const int EI0 = N_NODES * LAT + N_NODES * 4;
    const bool f32out = (*flag != 0);
    for (int k = 0; k < KNN; k++) nbr[gi * KNN + k] = bi[k];
    if (f32out) {
        float* o = (float*)d_out;
        for (int k = 0; k < KNN; k++) {
            o[EI0 + gi * KNN + k]      = (float)bi[k];
            o[EI0 + NK + gi * KNN + k] = (float)gi;
        }
    } else {
        bf16* o = (bf16*)d_out;
        for (int k = 0; k < KNN; k++) {
            o[EI0 + gi * KNN + k]      = f2bf((float)bi[k]);
            o[EI0 + NK + gi * KNN + k] = f2bf((float)gi);
        }
    }
}

// -------- GIN layer: hout = hin + mlp(hin + sum_nbr hin), 8 nodes/block ------
__global__ __launch_bounds__(256) void k_gin(
    const float* __restrict__ hin, float* __restrict__ hout,
    const int* __restrict__ nbr,
    const float* __restrict__ Wa, const float* __restrict__ ba,
    const float* __restrict__ Wb, const float* __restrict__ bb)
{
    __shared__ __align__(16) float sWa[LAT * HID];      // 32 KB, [f][u]
    __shared__ float sba[HID], sbb[LAT];
    __shared__ float sm[8 * LAT], sown[8 * LAT], st[8 * HID];
    __shared__ int   snbr[8 * KNN];
    const int tid = threadIdx.x;
    {   // stage Wa as float4
        const float4* g4 = (const float4*)Wa;
        float4* s4 = (float4*)sWa;
        for (int i = tid; i < LAT * HID / 4; i += 256) s4[i] = g4[i];
    }
    if (tid < HID) sba[tid] = ba[tid];
    if (tid < LAT) sbb[tid] = bb[tid];
    const int base = blockIdx.x * 8;
    if (tid < 8 * KNN) snbr[tid] = nbr[base * KNN + tid] & (N_NODES - 1);  // clamp-mask
    __syncthreads();
    // phase 1: m = own + sum of 15 neighbors
    #pragma unroll
    for (int p = 0; p < 2; p++) {
        const int e = tid + p * 256, n = e >> 6, f = e & 63, gi = base + n;
        const float own = hin[gi * LAT + f];
        float acc = own;
        #pragma unroll
        for (int k = 0; k < KNN; k++) acc += hin[snbr[n * KNN + k] * LAT + f];
        sm[e] = acc; sown[e] = own;
    }
    __syncthreads();
    // phase 2: t = relu(m @ Wa + ba); thread = (node n, 4 consecutive u)
    {
        const int n = tid >> 5, ug = (tid & 31) * 4;
        float a0 = sba[ug], a1 = sba[ug + 1], a2 = sba[ug + 2], a3 = sba[ug + 3];
        for (int f = 0; f < LAT; f++) {
            const float mv = sm[n * LAT + f];
            const float4 w = *(const float4*)&sWa[f * HID + ug];
            a0 = fmaf(mv, w.x, a0); a1 = fmaf(mv, w.y, a1);
            a2 = fmaf(mv, w.z, a2); a3 = fmaf(mv, w.w, a3);
        }
        st[n * HID + ug]     = a0 > 0.f ? a0 : 0.f;
        st[n * HID + ug + 1] = a1 > 0.f ? a1 : 0.f;
        st[n * HID + ug + 2] = a2 > 0.f ? a2 : 0.f;
        st[n * HID + ug + 3] = a3 > 0.f ? a3 : 0.f;
    }
    __syncthreads();
    // phase 3: g = t @ Wb + bb (Wb from global/L2); hout = own + g
    if (tid < 128) {
        const int n = tid >> 4, fg = (tid & 15) * 4, gi = base + n;
        float a0 = sbb[fg], a1 = sbb[fg + 1], a2 = sbb[fg + 2], a3 = sbb[fg + 3];
        for (int u = 0; u < HID; u++) {
            const float tv = st[n * HID + u];
            const float4 w = *(const float4*)&Wb[u * LAT + fg];
            a0 = fmaf(tv, w.x, a0); a1 = fmaf(tv, w.y, a1);
            a2 = fmaf(tv, w.z, a2); a3 = fmaf(tv, w.w, a3);
        }
        float4 o;
        o.x = sown[n * LAT + fg]     + a0;
        o.y = sown[n * LAT + fg + 1] + a1;
        o.z = sown[n * LAT + fg + 2] + a2;
        o.w = sown[n * LAT + fg + 3] + a3;
        *(float4*)&hout[gi * LAT + fg] = o;
    }
}

// -------- out_emb + final stores, 4 nodes/block ------------------------------
__global__ __launch_bounds__(256) void k_out(
    const float* __restrict__ h, const int* __restrict__ flag,
    const float* __restrict__ W1, const float* __restrict__ b1,
    const float* __restrict__ W2, const float* __restrict__ b2,
    void* __restrict__ d_out)
{
    __shared__ float sW1[LAT * LAT];    // 16 KB
    __shared__ float sW2[LAT * 4];
    __shared__ float sb1[LAT], sb2[4];
    __shared__ float sh[4][LAT], st[4][LAT];
    const int tid = threadIdx.x;
    for (int i = tid; i < LAT * LAT; i += 256) sW1[i] = W1[i];
    if (tid < LAT * 4) sW2[tid] = W2[tid];
    if (tid < LAT) sb1[tid] = b1[tid];
    if (tid < 4)  sb2[tid] = b2[tid];
    __syncthreads();
    const int ln = tid >> 6, f = tid & 63;
    const int node = blockIdx.x * 4 + ln;
    const bool f32out = (*flag != 0);
    const float hv = h[node * LAT + f];
    sh[ln][f] = hv;
    if (f32out) ((float*)d_out)[node * LAT + f] = hv;       // output 0: final h
    else        ((bf16*)d_out)[node * LAT + f] = f2bf(hv);
    __syncthreads();
    float acc = sb1[f];
    for (int j = 0; j < LAT; j++) acc = fmaf(sh[ln][j], sW1[j * LAT + f], acc);
    acc = acc > 0.f ? acc : 0.01f * acc;            // leaky
    st[ln][f] = acc;
    __syncthreads();
    if (f < 4) {
        float a = sb2[f];
        for (int j = 0; j < LAT; j++) a = fmaf(st[ln][j], sW2[j * 4 + f], a);
        const int xo = N_NODES * LAT + node * 4 + f;        // output 1: x_emb
        if (f32out) ((float*)d_out)[xo] = a;
        else        ((bf16*)d_out)[xo] = f2bf(a);
    }
}

extern "C" void kernel_launch(void* const* d_in, const int* in_sizes, int n_in,
                              void* d_out, int out_size, void* d_ws, size_t ws_size,
                              hipStream_t stream)
{
    (void)in_sizes; (void)n_in; (void)out_size; (void)ws_size;
    char* ws = (char*)d_ws;
    int*   flag = (int*)(ws + OFF_FLAG);
    float* cvt  = (float*)(ws + OFF_CVT);
    float* hA   = (float*)(ws + OFF_HA);
    float* hB   = (float*)(ws + OFF_HB);
    float* pos  = (float*)(ws + OFF_POS);
    int*   nbr  = (int*)(ws + OFF_NBR);

    CvtArgs a;
    const int idx[17] = {0, 3, 4, 5, 6, 7, 8, 9, 10, 11, 12, 13, 14, 15, 16, 17, 18};
    const int off[18] = {FO_X, FO_SE1, FO_BSE1, FO_SE2, FO_BSE2, FO_G1A, FO_BG1A,
                         FO_G1B, FO_BG1B, FO_G2A, FO_BG2A, FO_G2B, FO_BG2B,
                         FO_OE1, FO_BOE1, FO_OE2, FO_BOE2, CVT_TOTAL};
    for (int i = 0; i < 17; i++) a.src[i] = d_in[idx[i]];
    for (int i = 0; i < 18; i++) a.off[i] = off[i];

    k_detect <<<1, 256, 0, stream>>>((const u32*)d_in[7], flag);
    k_convert<<<(CVT_TOTAL + 255) / 256, 256, 0, stream>>>(a, flag, cvt);
    k_space  <<<N_NODES / 4, 256, 0, stream>>>(cvt + FO_X, cvt + FO_SE1, cvt + FO_BSE1,
                                               cvt + FO_SE2, cvt + FO_BSE2, hA, pos);
    k_knn    <<<NEV, NPE, 0, stream>>>(pos, flag, nbr, d_out);
    k_gin    <<<N_NODES / 8, 256, 0, stream>>>(hA, hB, nbr, cvt + FO_G1A, cvt + FO_BG1A,
                                               cvt + FO_G1B, cvt + FO_BG1B);
    k_gin    <<<N_NODES / 8, 256, 0, stream>>>(hB, hA, nbr, cvt + FO_G2A, cvt + FO_BG2A,
                                               cvt + FO_G2B, cvt + FO_BG2B);
    k_out    <<<N_NODES / 4, 256, 0, stream>>>(hA, flag, cvt + FO_OE1, cvt + FO_BOE1,
                                               cvt + FO_OE2, cvt + FO_BOE2, d_out);
}

// Round 3
// 180.704 us; speedup vs baseline: 2.1751x; 2.1751x over previous
//
#include <hip/hip_runtime.h>

// LevelLayer: space_emb FFN -> kNN(k=15, per-event) -> 2x GIN(residual) -> out FFN
// N=8192 nodes, 32 events x 256, LAT=64, HID=128, FIN=4, FOUT=4, SPACE=3.
// Input float dtype is RUNTIME-DETECTED (bf16 vs fp32) from W_g1a bit patterns;
// all floating inputs are upcast to a canonical fp32 copy in d_ws, outputs are
// stored as bf16 or fp32 per the same flag.
// Outputs concatenated in d_out: h[8192*64] | x_emb[8192*4] | ei[2*122880].

#define N_NODES 8192
#define NPE     256
#define NEV     32
#define KNN     15
#define LAT     64
#define HID     128
#define NK      (N_NODES*KNN)

#define CVT_TOTAL 74820          // total floating input elements
// byte offsets in ws
#define OFF_FLAG 0
#define OFF_CVT  64
#define OFF_HA   400000          // %16 == 0
#define OFF_HB   (OFF_HA + 2097152)
#define OFF_POS  (OFF_HB + 2097152)
#define OFF_NBR  (OFF_POS + 98304)
// float-element offsets inside the cvt region
#define FO_X     0
#define FO_SE1   32768
#define FO_BSE1  33024
#define FO_SE2   33088
#define FO_BSE2  37184
#define FO_G1A   37248
#define FO_BG1A  45440
#define FO_G1B   45568
#define FO_BG1B  53760
#define FO_G2A   53824
#define FO_BG2A  62016
#define FO_G2B   62144
#define FO_BG2B  70336
#define FO_OE1   70400
#define FO_BOE1  74496
#define FO_OE2   74560
#define FO_BOE2  74816

typedef unsigned short bf16;
typedef unsigned int   u32;
typedef unsigned long long u64;

__device__ __forceinline__ float bf2f(bf16 s) {
    union { u32 u; float f; } v; v.u = ((u32)s) << 16; return v.f;
}
__device__ __forceinline__ bf16 f2bf(float f) {
    union { float f; u32 u; } v; v.f = f;
    u32 u = v.u + 0x7fffu + ((v.u >> 16) & 1u);   // RNE
    return (bf16)(u >> 16);
}

// -------- dtype detect: inspect W_g1a's minimal footprint (16 KB) ------------
__global__ __launch_bounds__(256) void k_detect(const u32* __restrict__ w, int* __restrict__ flag)
{
    __shared__ int red[256];
    const int tid = threadIdx.x;
    int c = 0;
    for (int i = tid; i < 4096; i += 256) {
        const u32 x = w[i];
        c += ((x >> 7)  & 0xffu) >= 0xC8u;   // low half as bf16: |v| >= 2^73 -> insane
        c += ((x >> 23) & 0xffu) >= 0xC8u;   // high half
    }
    red[tid] = c;
    __syncthreads();
    for (int s = 128; s > 0; s >>= 1) {
        if (tid < s) red[tid] += red[tid + s];
        __syncthreads();
    }
    if (tid == 0) *flag = (red[0] > 64) ? 1 : 0;   // 1 = inputs are fp32
}

// -------- convert all floating inputs to fp32 in ws --------------------------
struct CvtArgs { const void* src[17]; int off[18]; };

__global__ __launch_bounds__(256) void k_convert(CvtArgs a, const int* __restrict__ flag,
                                                 float* __restrict__ dst)
{
    const int i = blockIdx.x * 256 + threadIdx.x;
    if (i >= CVT_TOTAL) return;
    int t = 0;
    while (i >= a.off[t + 1]) ++t;
    const int l = i - a.off[t];
    dst[i] = (*flag) ? ((const float*)a.src[t])[l]
                     : bf2f(((const bf16*)a.src[t])[l]);
}

// -------- space_emb: h = leaky(x@W1+b1)@W2+b2, 4 nodes/block ------------------
__global__ __launch_bounds__(256) void k_space(
    const float* __restrict__ x,
    const float* __restrict__ W1, const float* __restrict__ b1,
    const float* __restrict__ W2, const float* __restrict__ b2,
    float* __restrict__ h, float* __restrict__ pos)
{
    __shared__ float sW1[4 * LAT];
    __shared__ float sW2[LAT * LAT];
    __shared__ float sb1[LAT], sb2[LAT];
    __shared__ float shid[4][LAT];
    const int tid = threadIdx.x;
    for (int i = tid; i < 4 * LAT; i += 256)   sW1[i] = W1[i];
    for (int i = tid; i < LAT * LAT; i += 256) sW2[i] = W2[i];
    if (tid < LAT) { sb1[tid] = b1[tid]; sb2[tid] = b2[tid]; }
    __syncthreads();
    const int ln = tid >> 6, f = tid & 63;
    const int node = blockIdx.x * 4 + ln;
    float acc = sb1[f];
    #pragma unroll
    for (int i = 0; i < 4; i++) acc = fmaf(x[node * 4 + i], sW1[i * LAT + f], acc);
    acc = acc > 0.f ? acc : 0.01f * acc;          // leaky
    shid[ln][f] = acc;
    __syncthreads();
    float a2 = sb2[f];
    #pragma unroll
    for (int j = 0; j < LAT; j++) a2 = fmaf(shid[ln][j], sW2[j * LAT + f], a2);
    h[node * LAT + f] = a2;
    if (f < 3) pos[node * 3 + f] = a2;
}

// -------- kNN: one WAVE per node, register-resident u64-key extraction -------
// key = (dist_bits << 32) | local_j : u64-min == (smallest dist, lowest index),
// exactly jax.lax.top_k tie-break. No runtime-indexed arrays -> no scratch.
__global__ __launch_bounds__(256) void k_knn(
    const float* __restrict__ pos, const int* __restrict__ flag,
    int* __restrict__ nbr, void* __restrict__ d_out)
{
    __shared__ float sp[NPE * 3];
    const int tid = threadIdx.x;
    const int wave = tid >> 6, lane = tid & 63;
    const int node0 = blockIdx.x * 4;            // 4 nodes (waves) per block
    const int eb = node0 & ~(NPE - 1);           // event base (256 | node0 range)
    for (int i = tid; i < NPE * 3; i += 256) sp[i] = pos[(size_t)eb * 3 + i];
    __syncthreads();
    const int n  = node0 + wave;                 // this wave's node (global)
    const int nl = n - eb;                       // local node idx in event
    const float px = sp[nl * 3], py = sp[nl * 3 + 1], pz = sp[nl * 3 + 2];
    u64 key[4];
    #pragma unroll
    for (int c = 0; c < 4; c++) {
        const int j = 64 * c + lane;
        const float dx = px - sp[j * 3], dy = py - sp[j * 3 + 1], dz = pz - sp[j * 3 + 2];
        // match numpy fp32 ((x^2 + y^2) + z^2), contraction suppressed
        float dd = __fmul_rn(dx, dx);
        dd = __fadd_rn(dd, __fmul_rn(dy, dy));
        dd = __fadd_rn(dd, __fmul_rn(dz, dz));
        key[c] = ((u64)__float_as_uint(dd) << 32) | (u32)j;
        if (j == nl) key[c] = ~0ull;             // exclude self
    }
    u64 lmin = key[0] < key[1] ? key[0] : key[1];
    { u64 t = key[2] < key[3] ? key[2] : key[3]; lmin = t < lmin ? t : lmin; }
    int myj = 0;                                  // lane k keeps the k-th winner
    #pragma unroll
    for (int k = 0; k < KNN; k++) {
        u64 m = lmin;
        #pragma unroll
        for (int s = 32; s >= 1; s >>= 1) {      // butterfly min over 64 lanes
            const u64 o = __shfl_xor(m, s, 64);
            m = o < m ? o : m;
        }
        if (lane == k) myj = (int)(u32)m;        // winner's local index
        #pragma unroll
        for (int c = 0; c < 4; c++) if (key[c] == m) key[c] = ~0ull;  // consume
        lmin = key[0] < key[1] ? key[0] : key[1];
        { u64 t = key[2] < key[3] ? key[2] : key[3]; lmin = t < lmin ? t : lmin; }
    }
    if (lane < KNN) {
        const int gj  = eb + myj;
        const int EI0 = N_NODES * LAT + N_NODES * 4;
        nbr[n * KNN + lane] = gj;
        if (*flag) {
            float* o = (float*)d_out;
            o[EI0 + n * KNN + lane]      = (float)gj;
            o[EI0 + NK + n * KNN + lane] = (float)n;
        } else {
            bf16* o = (bf16*)d_out;
            o[EI0 + n * KNN + lane]      = f2bf((float)gj);
            o[EI0 + NK + n * KNN + lane] = f2bf((float)n);
        }
    }
}

// -------- GIN layer: hout = hin + mlp(hin + sum_nbr hin), 8 nodes/block ------
__global__ __launch_bounds__(256) void k_gin(
    const float* __restrict__ hin, float* __restrict__ hout,
    const int* __restrict__ nbr,
    const float* __restrict__ Wa, const float* __restrict__ ba,
    const float* __restrict__ Wb, const float* __restrict__ bb)
{
    __shared__ __align__(16) float sWa[LAT * HID];      // 32 KB, [f][u]
    __shared__ __align__(16) float sWb[HID * LAT];      // 32 KB, [u][f]
    __shared__ float sba[HID], sbb[LAT];
    __shared__ float sm[8 * LAT], sown[8 * LAT], st[8 * HID];
    __shared__ int   snbr[8 * KNN];
    const int tid = threadIdx.x;
    {   // stage Wa, Wb as float4
        const float4* ga = (const float4*)Wa;
        const float4* gb = (const float4*)Wb;
        float4* sa = (float4*)sWa;
        float4* sb = (float4*)sWb;
        for (int i = tid; i < LAT * HID / 4; i += 256) { sa[i] = ga[i]; sb[i] = gb[i]; }
    }
    if (tid < HID) sba[tid] = ba[tid];
    if (tid < LAT) sbb[tid] = bb[tid];
    const int base = blockIdx.x * 8;
    if (tid < 8 * KNN) snbr[tid] = nbr[base * KNN + tid] & (N_NODES - 1);  // clamp-mask
    __syncthreads();
    // phase 1: m = own + sum of 15 neighbors
    #pragma unroll
    for (int p = 0; p < 2; p++) {
        const int e = tid + p * 256, n = e >> 6, f = e & 63, gi = base + n;
        const float own = hin[gi * LAT + f];
        float acc = own;
        #pragma unroll
        for (int k = 0; k < KNN; k++) acc += hin[snbr[n * KNN + k] * LAT + f];
        sm[e] = acc; sown[e] = own;
    }
    __syncthreads();
    // phase 2: t = relu(m @ Wa + ba); thread = (node n, 4 consecutive u)
    {
        const int n = tid >> 5, ug = (tid & 31) * 4;
        float a0 = sba[ug], a1 = sba[ug + 1], a2 = sba[ug + 2], a3 = sba[ug + 3];
        for (int f = 0; f < LAT; f++) {
            const float mv = sm[n * LAT + f];
            const float4 w = *(const float4*)&sWa[f * HID + ug];
            a0 = fmaf(mv, w.x, a0); a1 = fmaf(mv, w.y, a1);
            a2 = fmaf(mv, w.z, a2); a3 = fmaf(mv, w.w, a3);
        }
        st[n * HID + ug]     = a0 > 0.f ? a0 : 0.f;
        st[n * HID + ug + 1] = a1 > 0.f ? a1 : 0.f;
        st[n * HID + ug + 2] = a2 > 0.f ? a2 : 0.f;
        st[n * HID + ug + 3] = a3 > 0.f ? a3 : 0.f;
    }
    __syncthreads();
    // phase 3: g = t @ Wb + bb; all 256 threads: thread = (node n, 2 consecutive f)
    {
        const int n = tid >> 5, fp = (tid & 31) * 2, gi = base + n;
        float a0 = sbb[fp], a1 = sbb[fp + 1];
        for (int u = 0; u < HID; u++) {
            const float tv = st[n * HID + u];
            const float2 w = *(const float2*)&sWb[u * LAT + fp];
            a0 = fmaf(tv, w.x, a0); a1 = fmaf(tv, w.y, a1);
        }
        float2 o;
        o.x = sown[n * LAT + fp]     + a0;
        o.y = sown[n * LAT + fp + 1] + a1;
        *(float2*)&hout[gi * LAT + fp] = o;
    }
}

// -------- out_emb + final stores, 4 nodes/block ------------------------------
__global__ __launch_bounds__(256) void k_out(
    const float* __restrict__ h, const int* __restrict__ flag,
    const float* __restrict__ W1, const float* __restrict__ b1,
    const float* __restrict__ W2, const float* __restrict__ b2,
    void* __restrict__ d_out)
{
    __shared__ float sW1[LAT * LAT];    // 16 KB
    __shared__ float sW2[LAT * 4];
    __shared__ float sb1[LAT], sb2[4];
    __shared__ float sh[4][LAT], st[4][LAT];
    const int tid = threadIdx.x;
    for (int i = tid; i < LAT * LAT; i += 256) sW1[i] = W1[i];
    if (tid < LAT * 4) sW2[tid] = W2[tid];
    if (tid < LAT) sb1[tid] = b1[tid];
    if (tid < 4)  sb2[tid] = b2[tid];
    __syncthreads();
    const int ln = tid >> 6, f = tid & 63;
    const int node = blockIdx.x * 4 + ln;
    const bool f32out = (*flag != 0);
    const float hv = h[node * LAT + f];
    sh[ln][f] = hv;
    if (f32out) ((float*)d_out)[node * LAT + f] = hv;       // output 0: final h
    else        ((bf16*)d_out)[node * LAT + f] = f2bf(hv);
    __syncthreads();
    float acc = sb1[f];
    for (int j = 0; j < LAT; j++) acc = fmaf(sh[ln][j], sW1[j * LAT + f], acc);
    acc = acc > 0.f ? acc : 0.01f * acc;            // leaky
    st[ln][f] = acc;
    __syncthreads();
    if (f < 4) {
        float a = sb2[f];
        for (int j = 0; j < LAT; j++) a = fmaf(st[ln][j], sW2[j * 4 + f], a);
        const int xo = N_NODES * LAT + node * 4 + f;        // output 1: x_emb
        if (f32out) ((float*)d_out)[xo] = a;
        else        ((bf16*)d_out)[xo] = f2bf(a);
    }
}

extern "C" void kernel_launch(void* const* d_in, const int* in_sizes, int n_in,
                              void* d_out, int out_size, void* d_ws, size_t ws_size,
                              hipStream_t stream)
{
    (void)in_sizes; (void)n_in; (void)out_size; (void)ws_size;
    char* ws = (char*)d_ws;
    int*   flag = (int*)(ws + OFF_FLAG);
    float* cvt  = (float*)(ws + OFF_CVT);
    float* hA   = (float*)(ws + OFF_HA);
    float* hB   = (float*)(ws + OFF_HB);
    float* pos  = (float*)(ws + OFF_POS);
    int*   nbr  = (int*)(ws + OFF_NBR);

    CvtArgs a;
    const int idx[17] = {0, 3, 4, 5, 6, 7, 8, 9, 10, 11, 12, 13, 14, 15, 16, 17, 18};
    const int off[18] = {FO_X, FO_SE1, FO_BSE1, FO_SE2, FO_BSE2, FO_G1A, FO_BG1A,
                         FO_G1B, FO_BG1B, FO_G2A, FO_BG2A, FO_G2B, FO_BG2B,
                         FO_OE1, FO_BOE1, FO_OE2, FO_BOE2, CVT_TOTAL};
    for (int i = 0; i < 17; i++) a.src[i] = d_in[idx[i]];
    for (int i = 0; i < 18; i++) a.off[i] = off[i];

    k_detect <<<1, 256, 0, stream>>>((const u32*)d_in[7], flag);
    k_convert<<<(CVT_TOTAL + 255) / 256, 256, 0, stream>>>(a, flag, cvt);
    k_space  <<<N_NODES / 4, 256, 0, stream>>>(cvt + FO_X, cvt + FO_SE1, cvt + FO_BSE1,
                                               cvt + FO_SE2, cvt + FO_BSE2, hA, pos);
    k_knn    <<<N_NODES / 4, 256, 0, stream>>>(pos, flag, nbr, d_out);
    k_gin    <<<N_NODES / 8, 256, 0, stream>>>(hA, hB, nbr, cvt + FO_G1A, cvt + FO_BG1A,
                                               cvt + FO_G1B, cvt + FO_BG1B);
    k_gin    <<<N_NODES / 8, 256, 0, stream>>>(hB, hA, nbr, cvt + FO_G2A, cvt + FO_BG2A,
                                               cvt + FO_G2B, cvt + FO_BG2B);
    k_out    <<<N_NODES / 4, 256, 0, stream>>>(hA, flag, cvt + FO_OE1, cvt + FO_BOE1,
                                               cvt + FO_OE2, cvt + FO_BOE2, d_out);
}